// Round 3
// baseline (1003.157 us; speedup 1.0000x reference)
//
#include <hip/hip_runtime.h>
#include <cmath>

// MuSeGNN on MI355X — round 3: comb-GEMM re-partition.
// r2 profile: comb-GEMM (157 blocks, K=640) was 88us at 6.5% occupancy /
// 12% VALUBusy — latency-bound on a starved grid. Now: skip-GEMM covers all
// 80000 rows (625 blocks; rows<10000 raw into hn), comb' = g@Wvstack only
// (K=512, 32x64 tile, 626 blocks) reading hn in its epilogue.
//
// Algebra (verified r1/r2, absmax 0.0): alpha_e = u[dst]·h[src] (+ softmax-
// invariant const; bk drops), u = h·(Wq_h Wk_h^T/√C) + bq·Wk_h^T/√C.
// out[dst] = mean_h((Σ_e a_e h[src])·Wv_h + bv_h) + h@Wskip + bskip; for
// deg=0 rows the attention term AND bv vanish (empty segment sum).

#define NN    10000
#define NTOT  80000
#define EE    320000
#define CH    128

__device__ __forceinline__ float rl_f(float v, int lane) {
    return __uint_as_float(__builtin_amdgcn_readlane(__float_as_uint(v), lane));
}

// ---------------------------------------------------------------------------
// Precompute folded weights: Pm (128x512), r (512), Wcomb (512x128 = Wv/4
// stacked (h,c)-major), bvbar, per-layer BN scale/bias.
// ---------------------------------------------------------------------------
__global__ __launch_bounds__(256) void precompute_kernel(
    const float* __restrict__ Wq, const float* __restrict__ bq,
    const float* __restrict__ Wk, const float* __restrict__ Wv,
    const float* __restrict__ bv,
    const float* __restrict__ bn_gamma, const float* __restrict__ bn_beta,
    const float* __restrict__ bn_mean, const float* __restrict__ bn_var,
    float* __restrict__ Pm, float* __restrict__ r,
    float* __restrict__ Wcomb, float* __restrict__ bvbar,
    float* __restrict__ bnS, float* __restrict__ bnB)
{
    const float inv_sqrtC = 0.08838834764831845f;  // 1/sqrt(128)
    int idx = blockIdx.x * 256 + threadIdx.x;
    if (idx < 65536) {            // Pm[c, o] = sum_{c'} Wq[c, h*128+c'] Wk[j, h*128+c'] /sqrtC
        int c = idx >> 9;
        int o = idx & 511;
        int hbase = o & ~127;
        int j = o & 127;
        const float* wq = Wq + c * 512 + hbase;
        const float* wk = Wk + j * 512 + hbase;
        float s = 0.f;
        for (int cc = 0; cc < 128; cc++) s = fmaf(wq[cc], wk[cc], s);
        Pm[c * 512 + o] = s * inv_sqrtC;
        return;
    }
    idx -= 65536;
    if (idx < 512) {              // r[o] = sum_{c'} bq[h*128+c'] Wk[j, h*128+c'] /sqrtC
        int o = idx, hbase = o & ~127, j = o & 127;
        const float* wk = Wk + j * 512 + hbase;
        const float* bqp = bq + hbase;
        float s = 0.f;
        for (int cc = 0; cc < 128; cc++) s = fmaf(bqp[cc], wk[cc], s);
        r[o] = s * inv_sqrtC;
        return;
    }
    idx -= 512;
    if (idx < 65536) {            // Wcomb[k, n], k=(h,c): Wv[c, h*128+n] / 4
        int k = idx >> 7;
        int n = idx & 127;
        int h = k >> 7, c = k & 127;
        Wcomb[k * 128 + n] = Wv[c * 512 + h * 128 + n] * 0.25f;
        return;
    }
    idx -= 65536;
    if (idx < 128) {              // bvbar = mean over heads of bv
        float s = 0.f;
        for (int h = 0; h < 4; h++) s += bv[h * 128 + idx];
        bvbar[idx] = 0.25f * s;
        return;
    }
    idx -= 128;
    if (idx < 384) {              // BN fold (eval): y = x*scale + bias
        float sc = bn_gamma[idx] / sqrtf(bn_var[idx] + 1e-5f);
        bnS[idx] = sc;
        bnB[idx] = bn_beta[idx] - bn_mean[idx] * sc;
        return;
    }
}

// ---------------------------------------------------------------------------
// CSR build by dst
// ---------------------------------------------------------------------------
__global__ void count_kernel(const int* __restrict__ dst, int* __restrict__ deg) {
    int e = blockIdx.x * 256 + threadIdx.x;
    if (e < EE) atomicAdd(&deg[dst[e]], 1);
}

__global__ __launch_bounds__(1024) void scan_kernel(const int* __restrict__ deg,
                                                    int* __restrict__ rowstart) {
    __shared__ int part[1024];
    const int t = threadIdx.x;
    int loc[10];
    int s = 0;
    for (int i = 0; i < 10; i++) {
        int idx = t * 10 + i;
        int v = (idx < NN) ? deg[idx] : 0;
        loc[i] = s; s += v;
    }
    part[t] = s; __syncthreads();
    for (int d = 1; d < 1024; d <<= 1) {
        int v = (t >= d) ? part[t - d] : 0;
        __syncthreads();
        part[t] += v;
        __syncthreads();
    }
    int base = (t == 0) ? 0 : part[t - 1];
    for (int i = 0; i < 10; i++) {
        int idx = t * 10 + i;
        if (idx <= NN) rowstart[idx] = base + loc[i];
    }
}

__global__ void scatter_kernel(const int* __restrict__ src, const int* __restrict__ dst,
                               const int* __restrict__ rowstart, int* __restrict__ cursor,
                               int* __restrict__ csr_src) {
    int e = blockIdx.x * 256 + threadIdx.x;
    if (e < EE) {
        int d = dst[e];
        int p = atomicAdd(&cursor[d], 1);
        csr_src[rowstart[d] + p] = src[e];
    }
}

// ---------------------------------------------------------------------------
// fp32 tiled GEMM, 256 threads, BK=16, vectorized LDS fragment reads.
// MODE 0: C = A*B + bias
// MODE 3: x = A*B + bias; rows >= rowSplit also get BN+relu   (skip, all rows)
// MODE 4: x = A*B + C_old + (deg>0)*bias2; BN+relu; in-place  (comb')
// ---------------------------------------------------------------------------
template<int BM, int BN, int TM, int TN, int MODE>
__global__ __launch_bounds__(256) void gemm_fp32(
    const float* __restrict__ A, int lda,
    const float* __restrict__ B, int ldb,
    const float* __restrict__ bias, const float* __restrict__ bias2,
    const int* __restrict__ deg,
    const float* __restrict__ bnS, const float* __restrict__ bnB,
    float* __restrict__ C, int ldc, int M, int K, int rowSplit)
{
    constexpr int BK = 16;
    __shared__ float As[BK][BM + 4];
    __shared__ float Bs[BK][BN + 4];
    const int t  = threadIdx.x;
    const int tx = t % (BN / TN);
    const int ty = t / (BN / TN);
    const int m0 = blockIdx.x * BM;
    const int n0 = blockIdx.y * BN;
    float acc[TM][TN];
    #pragma unroll
    for (int i = 0; i < TM; i++)
        #pragma unroll
        for (int j = 0; j < TN; j++) acc[i][j] = 0.f;

    for (int k0 = 0; k0 < K; k0 += BK) {
        // A tile (BM x BK) -> As[k][m] (transposed)
        #pragma unroll
        for (int f = t; f < BM * 4; f += 256) {
            int row = f >> 2, fc = f & 3;
            int gm = m0 + row;
            float4 v = make_float4(0.f, 0.f, 0.f, 0.f);
            if (gm < M) v = *(const float4*)(A + (size_t)gm * lda + k0 + fc * 4);
            As[fc * 4 + 0][row] = v.x;
            As[fc * 4 + 1][row] = v.y;
            As[fc * 4 + 2][row] = v.z;
            As[fc * 4 + 3][row] = v.w;
        }
        // B tile (BK x BN)
        #pragma unroll
        for (int f = t; f < BK * (BN / 4); f += 256) {
            int kk = f / (BN / 4);
            int nn = (f % (BN / 4)) * 4;
            *(float4*)(&Bs[kk][nn]) = *(const float4*)(B + (size_t)(k0 + kk) * ldb + n0 + nn);
        }
        __syncthreads();
        #pragma unroll
        for (int kk = 0; kk < BK; kk++) {
            float af[TM], bf[TN];
            if constexpr (TM == 2) {
                float2 v = *(const float2*)&As[kk][ty * 2];
                af[0] = v.x; af[1] = v.y;
            } else {
                #pragma unroll
                for (int ii = 0; ii < TM; ii += 4) {
                    float4 v = *(const float4*)&As[kk][ty * TM + ii];
                    af[ii + 0] = v.x; af[ii + 1] = v.y; af[ii + 2] = v.z; af[ii + 3] = v.w;
                }
            }
            #pragma unroll
            for (int jj = 0; jj < TN; jj += 4) {
                float4 v = *(const float4*)&Bs[kk][tx * TN + jj];
                bf[jj + 0] = v.x; bf[jj + 1] = v.y; bf[jj + 2] = v.z; bf[jj + 3] = v.w;
            }
            #pragma unroll
            for (int i = 0; i < TM; i++)
                #pragma unroll
                for (int j = 0; j < TN; j++)
                    acc[i][j] = fmaf(af[i], bf[j], acc[i][j]);
        }
        __syncthreads();
    }
    // epilogue
    #pragma unroll
    for (int i = 0; i < TM; i++) {
        int gm = m0 + ty * TM + i;
        if (gm >= M) continue;
        const bool addB2 = (MODE == 4) ? (deg[gm] > 0) : false;
        #pragma unroll
        for (int j = 0; j < TN; j += 4) {
            float* cp = C + (size_t)gm * ldc + n0 + tx * TN + j;
            float4 old;
            if (MODE == 4) old = *(const float4*)cp;
            float4 v;
            float* vp = &v.x;
            const float* op = &old.x;
            #pragma unroll
            for (int q = 0; q < 4; q++) {
                int n = n0 + tx * TN + j + q;
                float x = acc[i][j + q];
                if (MODE == 4) {
                    x += op[q];
                    if (addB2) x += bias2[n];
                    x = fmaf(x, bnS[n], bnB[n]);
                    x = fmaxf(x, 0.f);
                } else {
                    x += bias[n];
                    if (MODE == 3 && gm >= rowSplit) {
                        x = fmaf(x, bnS[n], bnB[n]);
                        x = fmaxf(x, 0.f);
                    }
                }
                vp[q] = x;
            }
            *(float4*)cp = v;
        }
    }
}

// ---------------------------------------------------------------------------
// Attention: one block per dst node, chunked online softmax over CSR edges.
// ---------------------------------------------------------------------------
__global__ __launch_bounds__(256) void attn_kernel(
    const float* __restrict__ h,
    const float* __restrict__ u,
    float* __restrict__ g,
    const int* __restrict__ rowstart,
    const int* __restrict__ csr_src)
{
    __shared__ float h_lds[128 * 65];
    __shared__ __align__(16) float palpha[4 * 64 * 4];   // [ht][j][w]
    __shared__ __align__(16) float wT[64 * 4];           // [j][ht]
    __shared__ __align__(16) float scale_lds[4];
    __shared__ __align__(16) float s_lds[4];
    __shared__ __align__(16) float merge[128 * 4];
    __shared__ int src_lds[64];

    const int n  = blockIdx.x;
    const int t  = threadIdx.x;
    const int w  = t >> 6;      // wave id
    const int l  = t & 63;      // lane
    const int c  = t & 127;     // acc channel
    const int jh = t >> 7;      // acc j-half
    const int rs   = rowstart[n];
    const int degn = rowstart[n + 1] - rs;

    if (degn == 0) {
        g[(size_t)n * 512 + t] = 0.f;
        g[(size_t)n * 512 + 256 + t] = 0.f;
        return;
    }
    // wave-w's u slice: heads packed 2-per-register, c in [32w, 32w+32)
    float u_reg0 = u[(size_t)n * 512 + ((l >> 5)) * 128 + 32 * w + (l & 31)];
    float u_reg1 = u[(size_t)n * 512 + ((l >> 5) + 2) * 128 + 32 * w + (l & 31)];

    float m_run = -INFINITY, s_run = 0.f;   // head state for wave w (= head w)
    float4 acc4 = make_float4(0.f, 0.f, 0.f, 0.f);

    for (int base = 0; base < degn; base += 64) {
        const int len = min(64, degn - base);
        __syncthreads();
        if (t < len) src_lds[t] = csr_src[rs + base + t];
        __syncthreads();
        for (int f = t; f < len * 32; f += 256) {
            const int j = f >> 5, c4 = (f & 31) * 4;
            const float4 v = *(const float4*)(h + (size_t)src_lds[j] * CH + c4);
            h_lds[(c4 + 0) * 65 + j] = v.x;
            h_lds[(c4 + 1) * 65 + j] = v.y;
            h_lds[(c4 + 2) * 65 + j] = v.z;
            h_lds[(c4 + 3) * 65 + j] = v.w;
        }
        __syncthreads();
        // phase D: lane l = edge, c-range [32w, 32w+32), 4 head-partials
        {
            float p0 = 0.f, p1 = 0.f, p2 = 0.f, p3 = 0.f;
            #pragma unroll
            for (int dc = 0; dc < 32; dc++) {
                const float hv = h_lds[(32 * w + dc) * 65 + l];
                p0 = fmaf(rl_f(u_reg0, dc),      hv, p0);
                p1 = fmaf(rl_f(u_reg0, 32 + dc), hv, p1);
                p2 = fmaf(rl_f(u_reg1, dc),      hv, p2);
                p3 = fmaf(rl_f(u_reg1, 32 + dc), hv, p3);
            }
            palpha[(0 * 64 + l) * 4 + w] = p0;
            palpha[(1 * 64 + l) * 4 + w] = p1;
            palpha[(2 * 64 + l) * 4 + w] = p2;
            palpha[(3 * 64 + l) * 4 + w] = p3;
        }
        __syncthreads();
        // phase S: wave w = head w, online softmax over this chunk
        {
            const float4 pa = *(const float4*)&palpha[(w * 64 + l) * 4];
            float alpha = (l < len) ? (pa.x + pa.y + pa.z + pa.w) : -INFINITY;
            float mx = alpha;
            #pragma unroll
            for (int d = 1; d < 64; d <<= 1) mx = fmaxf(mx, __shfl_xor(mx, d, 64));
            const float newm = fmaxf(m_run, mx);
            float e = (l < len) ? __expf(alpha - newm) : 0.f;
            float ss = e;
            #pragma unroll
            for (int d = 1; d < 64; d <<= 1) ss += __shfl_xor(ss, d, 64);
            const float sc = (m_run == -INFINITY) ? 0.f : __expf(m_run - newm);
            s_run = s_run * sc + ss;
            m_run = newm;
            wT[l * 4 + w] = e;
            if (l == 0) scale_lds[w] = sc;
        }
        __syncthreads();
        // phase A: thread owns channel c, half of j range; acc per head
        {
            const float4 scv = *(const float4*)scale_lds;
            acc4.x *= scv.x; acc4.y *= scv.y; acc4.z *= scv.z; acc4.w *= scv.w;
            const int j0 = jh * 32;
            const int j1 = min(len, j0 + 32);
            for (int j = j0; j < j1; j++) {
                const float hv = h_lds[c * 65 + j];
                const float4 wv = *(const float4*)&wT[j * 4];
                acc4.x = fmaf(wv.x, hv, acc4.x);
                acc4.y = fmaf(wv.y, hv, acc4.y);
                acc4.z = fmaf(wv.z, hv, acc4.z);
                acc4.w = fmaf(wv.w, hv, acc4.w);
            }
        }
    }
    if (l == 0) s_lds[w] = s_run;
    __syncthreads();
    if (jh == 1) *(float4*)&merge[c * 4] = acc4;
    __syncthreads();
    if (jh == 0) {
        const float4 o  = *(const float4*)&merge[c * 4];
        const float4 sv = *(const float4*)s_lds;
        g[(size_t)n * 512 + 0 * 128 + c] = (acc4.x + o.x) / (sv.x + 1e-16f);
        g[(size_t)n * 512 + 1 * 128 + c] = (acc4.y + o.y) / (sv.y + 1e-16f);
        g[(size_t)n * 512 + 2 * 128 + c] = (acc4.z + o.z) / (sv.z + 1e-16f);
        g[(size_t)n * 512 + 3 * 128 + c] = (acc4.w + o.w) / (sv.w + 1e-16f);
    }
}

// ---------------------------------------------------------------------------
// Radix-select sort-pool: per graph, exact top-30 by channel 127 desc
// (ties -> lower index), matching numpy's stable argsort of negated keys.
// Keys are post-ReLU (>= +0.0) so float bits are order-preserving as uint32.
// ---------------------------------------------------------------------------
__global__ __launch_bounds__(256) void radix_pool_kernel(
    const float* __restrict__ h3, const float* __restrict__ age,
    float* __restrict__ z)
{
    __shared__ unsigned int keys[NN];            // 40 KB
    __shared__ int hist[256];
    __shared__ int sbuf[256];
    __shared__ unsigned int sel_prefix;
    __shared__ int sel_need;
    __shared__ int gt_counter;
    __shared__ unsigned int cand_key[30];
    __shared__ int cand_idx[30];
    __shared__ int order[30];

    const int b = blockIdx.x;
    const int t = threadIdx.x;

    for (int i = t; i < NN; i += 256)
        keys[i] = __float_as_uint(h3[((size_t)b * NN + i) * CH + 127]);
    if (t == 0) { sel_prefix = 0u; sel_need = 30; gt_counter = 0; }
    __syncthreads();

    // 4 MSB-first radix rounds
    for (int r = 3; r >= 0; r--) {
        hist[t] = 0;
        __syncthreads();
        const int shift = r * 8;
        const unsigned int pmask = (r == 3) ? 0u : (0xFFFFFFFFu << ((r + 1) * 8));
        const unsigned int pref = sel_prefix;
        const int need = sel_need;
        for (int i = t; i < NN; i += 256) {
            unsigned int k = keys[i];
            if ((k & pmask) == pref)
                atomicAdd(&hist[(k >> shift) & 255u], 1);
        }
        __syncthreads();
        // parallel suffix-sum: sbuf[t] = sum of hist[255-t .. 255]
        sbuf[t] = hist[255 - t];
        __syncthreads();
        for (int d = 1; d < 256; d <<= 1) {
            int o = (t >= d) ? sbuf[t - d] : 0;
            __syncthreads();
            sbuf[t] += o;
            __syncthreads();
        }
        {
            const int v = t;                       // candidate bucket
            const int ge = sbuf[255 - v];          // # keys in buckets >= v
            const int gt = ge - hist[v];           // # keys in buckets >  v
            if (gt < need && need <= ge) {         // exactly one v matches
                sel_prefix = pref | ((unsigned int)v << shift);
                sel_need = need - gt;
            }
        }
        __syncthreads();
    }

    const unsigned int T = sel_prefix;             // exact rank-30 key value
    const int need_eq = sel_need;                  // ties at T to take
    const int n_gt = 30 - need_eq;                 // strictly-greater count

    // collect keys > T (unordered; final rank sort fixes order)
    for (int i = t; i < NN; i += 256) {
        unsigned int k = keys[i];
        if (k > T) {
            int p = atomicAdd(&gt_counter, 1);
            cand_key[p] = k; cand_idx[p] = i;
        }
    }
    // stable tie selection: need_eq smallest indices among keys == T
    {
        const int CHK = (NN + 255) / 256;          // 40
        const int i0 = t * CHK, i1 = min(NN, i0 + CHK);
        int local = 0;
        for (int i = i0; i < i1; i++) if (keys[i] == T) local++;
        sbuf[t] = local;
        __syncthreads();
        for (int d = 1; d < 256; d <<= 1) {
            int o = (t >= d) ? sbuf[t - d] : 0;
            __syncthreads();
            sbuf[t] += o;
            __syncthreads();
        }
        int rank = (t == 0) ? 0 : sbuf[t - 1];
        for (int i = i0; i < i1; i++) {
            if (keys[i] == T) {
                if (rank < need_eq) { cand_key[n_gt + rank] = T; cand_idx[n_gt + rank] = i; }
                rank++;
            }
        }
    }
    __syncthreads();
    // rank 30 candidates by (key desc, idx asc) — all-pairs, unique ranks
    if (t < 30) {
        const unsigned int mk = cand_key[t];
        const int mi = cand_idx[t];
        int rk = 0;
        for (int j = 0; j < 30; j++) {
            const unsigned int ok = cand_key[j];
            const int oi = cand_idx[j];
            if (ok > mk || (ok == mk && oi < mi)) rk++;
        }
        order[rk] = t;
    }
    __syncthreads();
    for (int f = t; f < 30 * CH; f += 256) {
        int kk = f >> 7, cc = f & 127;
        z[(size_t)b * 3841 + f] = h3[((size_t)b * NN + cand_idx[order[kk]]) * CH + cc];
    }
    if (t == 0) z[(size_t)b * 3841 + 3840] = age[b];
}

// ---------------------------------------------------------------------------
// MLP: z(8x3841) @ W1[0:3841,:512]  (zero-padded rows of W1 skipped entirely)
// ---------------------------------------------------------------------------
__global__ __launch_bounds__(256) void mlp1_kernel(
    const float* __restrict__ z, const float* __restrict__ W1,
    float* __restrict__ zh)   // zh pre-zeroed; b1 added in mlp2
{
    __shared__ float zs[256];
    const int b  = blockIdx.x >> 4;
    const int ic = blockIdx.x & 15;
    const int t  = threadIdx.x;
    const int i0 = ic * 241;
    const int i1 = min(3841, i0 + 241);
    float a0 = 0.f, a1 = 0.f;
    for (int cb = i0; cb < i1; cb += 256) {
        int cl = min(256, i1 - cb);
        __syncthreads();
        if (t < cl) zs[t] = z[(size_t)b * 3841 + cb + t];
        __syncthreads();
        #pragma unroll 4
        for (int q = 0; q < cl; q++) {
            float zv = zs[q];
            const float* wp = W1 + (size_t)(cb + q) * 512;
            a0 = fmaf(zv, wp[t], a0);
            a1 = fmaf(zv, wp[t + 256], a1);
        }
    }
    atomicAdd(&zh[(size_t)b * 512 + t], a0);
    atomicAdd(&zh[(size_t)b * 512 + t + 256], a1);
}

__global__ __launch_bounds__(256) void mlp2_kernel(
    const float* __restrict__ zh, const float* __restrict__ b1,
    const float* __restrict__ W2, const float* __restrict__ b2,
    float* __restrict__ out)
{
    __shared__ float r0[256], r1[256];
    const int b = blockIdx.x;
    const int t = threadIdx.x;
    float a0 = 0.f, a1 = 0.f;
    for (int j = t; j < 512; j += 256) {
        float v = fmaxf(zh[(size_t)b * 512 + j] + b1[j], 0.f);
        a0 = fmaf(v, W2[j * 2 + 0], a0);
        a1 = fmaf(v, W2[j * 2 + 1], a1);
    }
    r0[t] = a0; r1[t] = a1; __syncthreads();
    for (int s = 128; s > 0; s >>= 1) {
        if (t < s) { r0[t] += r0[t + s]; r1[t] += r1[t + s]; }
        __syncthreads();
    }
    if (t == 0) {
        float l0 = r0[0] + b2[0], l1 = r1[0] + b2[1];
        float m = fmaxf(l0, l1);
        float lse = m + logf(__expf(l0 - m) + __expf(l1 - m));
        out[b * 2 + 0] = l0 - lse;
        out[b * 2 + 1] = l1 - lse;
    }
}

// ---------------------------------------------------------------------------
extern "C" void kernel_launch(void* const* d_in, const int* in_sizes, int n_in,
                              void* d_out, int out_size, void* d_ws, size_t ws_size,
                              hipStream_t stream) {
    const float* x     = (const float*)d_in[0];
    const int*   ei    = (const int*)d_in[1];
    const float* age   = (const float*)d_in[2];
    const float* Wq    = (const float*)d_in[3];
    const float* bq    = (const float*)d_in[4];
    const float* Wk    = (const float*)d_in[5];
    // d_in[6] = bk: provably softmax-invariant, unused.
    const float* Wv    = (const float*)d_in[7];
    const float* bv    = (const float*)d_in[8];
    const float* Wskip = (const float*)d_in[9];
    const float* bskip = (const float*)d_in[10];
    const float* bn_g  = (const float*)d_in[11];
    const float* bn_b  = (const float*)d_in[12];
    const float* bn_m  = (const float*)d_in[13];
    const float* bn_v  = (const float*)d_in[14];
    const float* W1    = (const float*)d_in[15];
    const float* b1    = (const float*)d_in[16];
    const float* W2    = (const float*)d_in[17];
    const float* b2    = (const float*)d_in[18];

    float* ws = (float*)d_ws;
    float* hA    = ws;                       // 10,240,000
    float* hB    = hA + 10240000;            // 10,240,000
    float* u     = hB + 10240000;            // 5,120,000 (g aliases u)
    float* Pm    = u + 5120000;              // 65,536
    float* r_    = Pm + 65536;               // 512
    float* Wcomb = r_ + 512;                 // 65,536
    float* bvbar = Wcomb + 65536;            // 128
    float* bnS   = bvbar + 128;              // 384
    float* bnB   = bnS + 384;                // 384
    float* zbuf  = bnB + 384;                // 30,728
    float* zh    = zbuf + 30728;             // 4,096
    int* deg      = (int*)(zh + 4096);       // 10,000
    int* cursor   = deg + NN;                // 10,000
    int* rowstart = cursor + NN;             // 10,001
    int* csr_src  = rowstart + NN + 1;       // 320,000

    const int* srcI = ei;
    const int* dstI = ei + EE;

    hipMemsetAsync(deg, 0, sizeof(int) * (2 * NN), stream);   // deg + cursor
    hipMemsetAsync(zh, 0, sizeof(float) * 4096, stream);

    precompute_kernel<<<516, 256, 0, stream>>>(Wq, bq, Wk, Wv, bv,
                                               bn_g, bn_b, bn_m, bn_v,
                                               Pm, r_, Wcomb, bvbar, bnS, bnB);
    count_kernel<<<1250, 256, 0, stream>>>(dstI, deg);
    scan_kernel<<<1, 1024, 0, stream>>>(deg, rowstart);
    scatter_kernel<<<1250, 256, 0, stream>>>(srcI, dstI, rowstart, cursor, csr_src);

    const float* hcur = x;
    float* hn = hA;
    for (int l = 0; l < 3; l++) {
        // u = h[0:10000] @ Pm + r                       (316 blocks)
        gemm_fp32<128, 128, 8, 8, 0><<<dim3(79, 4), 256, 0, stream>>>(
            hcur, CH, Pm, 512, r_, nullptr, nullptr, nullptr, nullptr,
            u, 512, NN, 128, 0);
        // g = softmax-weighted neighbor sums of h, aliased onto u
        attn_kernel<<<NN, 256, 0, stream>>>(hcur, u, u, rowstart, csr_src);
        // ALL 80000 rows: hn = h @ Wskip + bskip; rows >= NN get BN+relu,
        // rows < NN stay raw for comb' to finish        (625 blocks)
        gemm_fp32<128, 128, 8, 8, 3><<<dim3(625, 1), 256, 0, stream>>>(
            hcur, CH, Wskip, 128, bskip, nullptr, nullptr,
            bnS + l * 128, bnB + l * 128, hn, CH, NTOT, 128, NN);
        // rows < NN: hn = relu(bn(g @ Wvstack + hn + (deg>0)*bvbar))  (626 blocks)
        gemm_fp32<32, 64, 2, 4, 4><<<dim3(313, 2), 256, 0, stream>>>(
            u, 512, Wcomb, 128, nullptr, bvbar, deg,
            bnS + l * 128, bnB + l * 128, hn, CH, NN, 512, 0);
        hcur = hn;
        hn = (l == 0) ? hB : hA;
    }
    // hcur == hA holds the final layer output
    radix_pool_kernel<<<8, 256, 0, stream>>>(hcur, age, zbuf);
    mlp1_kernel<<<128, 256, 0, stream>>>(zbuf, W1, zh);
    mlp2_kernel<<<8, 256, 0, stream>>>(zh, b1, W2, b2, (float*)d_out);
}

// Round 4
// 850.825 us; speedup vs baseline: 1.1790x; 1.1790x over previous
//
#include <hip/hip_runtime.h>
#include <cmath>

// MuSeGNN on MI355X — round 4: upper-row 3-layer fusion + lean lower loop.
//
// r3 profile: 80000-row skip GEMM = 107us x3 at 19% VALUBusy / 20% occupancy
// (625 blocks, latency-bound). Fixes here:
//  1. Rows >= 10000 feed nothing but the final pool; their 3-layer affine+relu
//     chain (shared Wskip!) is fused into ONE kernel with the 64-row tile
//     LDS-resident across layers: 41MB read+write once instead of 3x.
//  2. Per-layer loop now touches only rows < 10000. Lower skip columns are
//     folded into the u-GEMM (B = [Pm | Wskip], N=640) -> h_low read once.
//  3. GEMMs re-tiled 64x64 (TM=TN=4) for block counts ~1570 (occupancy).
//
// Algebra (verified r1-r3, absmax 0.0): alpha_e = u[dst]·h[src] (+softmax-
// invariant const; bk drops), u = h·(Wq_h Wk_h^T/√C) + bq·Wk_h^T/√C.
// out[dst] = mean_h((Σ_e a_e h[src])·Wv_h + bv_h) + h@Wskip + bskip; deg=0
// rows lose the attention term AND bv (empty segment sum).

#define NN    10000
#define NTOT  80000
#define EE    320000
#define CH    128

__device__ __forceinline__ float rl_f(float v, int lane) {
    return __uint_as_float(__builtin_amdgcn_readlane(__float_as_uint(v), lane));
}

// ---------------------------------------------------------------------------
// Precompute: Bcat (128x640 = [Pm | Wskip]), biascat (640 = [r | bskip]),
// Wcomb (512x128 = Wv/4 stacked (h,c)-major), bvbar, BN scale/bias.
// ---------------------------------------------------------------------------
__global__ __launch_bounds__(256) void precompute_kernel(
    const float* __restrict__ Wq, const float* __restrict__ bq,
    const float* __restrict__ Wk, const float* __restrict__ Wv,
    const float* __restrict__ bv, const float* __restrict__ Wskip,
    const float* __restrict__ bskip,
    const float* __restrict__ bn_gamma, const float* __restrict__ bn_beta,
    const float* __restrict__ bn_mean, const float* __restrict__ bn_var,
    float* __restrict__ Bcat, float* __restrict__ biascat,
    float* __restrict__ Wcomb, float* __restrict__ bvbar,
    float* __restrict__ bnS, float* __restrict__ bnB)
{
    const float inv_sqrtC = 0.08838834764831845f;  // 1/sqrt(128)
    int idx = blockIdx.x * 256 + threadIdx.x;
    if (idx < 65536) {            // Pm part: Bcat[c, o] o<512
        int c = idx >> 9;
        int o = idx & 511;
        int hbase = o & ~127;
        int j = o & 127;
        const float* wq = Wq + c * 512 + hbase;
        const float* wk = Wk + j * 512 + hbase;
        float s = 0.f;
        for (int cc = 0; cc < 128; cc++) s = fmaf(wq[cc], wk[cc], s);
        Bcat[c * 640 + o] = s * inv_sqrtC;
        return;
    }
    idx -= 65536;
    if (idx < 16384) {            // Wskip part: Bcat[c, 512+n]
        int c = idx >> 7, n = idx & 127;
        Bcat[c * 640 + 512 + n] = Wskip[c * 128 + n];
        return;
    }
    idx -= 16384;
    if (idx < 512) {              // biascat[0..511] = r
        int o = idx, hbase = o & ~127, j = o & 127;
        const float* wk = Wk + j * 512 + hbase;
        const float* bqp = bq + hbase;
        float s = 0.f;
        for (int cc = 0; cc < 128; cc++) s = fmaf(bqp[cc], wk[cc], s);
        biascat[o] = s * inv_sqrtC;
        return;
    }
    idx -= 512;
    if (idx < 128) {              // biascat[512..639] = bskip
        biascat[512 + idx] = bskip[idx];
        return;
    }
    idx -= 128;
    if (idx < 65536) {            // Wcomb[k, n], k=(h,c): Wv[c, h*128+n] / 4
        int k = idx >> 7;
        int n = idx & 127;
        int h = k >> 7, c = k & 127;
        Wcomb[k * 128 + n] = Wv[c * 512 + h * 128 + n] * 0.25f;
        return;
    }
    idx -= 65536;
    if (idx < 128) {              // bvbar = mean over heads of bv
        float s = 0.f;
        for (int h = 0; h < 4; h++) s += bv[h * 128 + idx];
        bvbar[idx] = 0.25f * s;
        return;
    }
    idx -= 128;
    if (idx < 384) {              // BN fold (eval): y = x*scale + bias
        float sc = bn_gamma[idx] / sqrtf(bn_var[idx] + 1e-5f);
        bnS[idx] = sc;
        bnB[idx] = bn_beta[idx] - bn_mean[idx] * sc;
        return;
    }
}

// ---------------------------------------------------------------------------
// CSR build by dst
// ---------------------------------------------------------------------------
__global__ void count_kernel(const int* __restrict__ dst, int* __restrict__ deg) {
    int e = blockIdx.x * 256 + threadIdx.x;
    if (e < EE) atomicAdd(&deg[dst[e]], 1);
}

__global__ __launch_bounds__(1024) void scan_kernel(const int* __restrict__ deg,
                                                    int* __restrict__ rowstart) {
    __shared__ int part[1024];
    const int t = threadIdx.x;
    int loc[10];
    int s = 0;
    for (int i = 0; i < 10; i++) {
        int idx = t * 10 + i;
        int v = (idx < NN) ? deg[idx] : 0;
        loc[i] = s; s += v;
    }
    part[t] = s; __syncthreads();
    for (int d = 1; d < 1024; d <<= 1) {
        int v = (t >= d) ? part[t - d] : 0;
        __syncthreads();
        part[t] += v;
        __syncthreads();
    }
    int base = (t == 0) ? 0 : part[t - 1];
    for (int i = 0; i < 10; i++) {
        int idx = t * 10 + i;
        if (idx <= NN) rowstart[idx] = base + loc[i];
    }
}

__global__ void scatter_kernel(const int* __restrict__ src, const int* __restrict__ dst,
                               const int* __restrict__ rowstart, int* __restrict__ cursor,
                               int* __restrict__ csr_src) {
    int e = blockIdx.x * 256 + threadIdx.x;
    if (e < EE) {
        int d = dst[e];
        int p = atomicAdd(&cursor[d], 1);
        csr_src[rowstart[d] + p] = src[e];
    }
}

// ---------------------------------------------------------------------------
// Upper rows (>= NN): 3-layer relu(bn(h@Wskip+bskip)) chain, tile resident
// in LDS across layers. Sequential-k accumulation == reference association.
// 64 rows/block, 256 threads (TM=4 rows x TN=8 cols per thread).
// ---------------------------------------------------------------------------
__global__ __launch_bounds__(256) void skip3_kernel(
    const float* __restrict__ xup,    // (NTOT-NN) x 128
    const float* __restrict__ Wskip,  // 128 x 128
    const float* __restrict__ bskip,
    const float* __restrict__ bnS, const float* __restrict__ bnB,  // [3][128]
    float* __restrict__ h3up)
{
    __shared__ float rowb[64][132];
    __shared__ float Bs[16][132];
    const int t = threadIdx.x;
    const int r0 = blockIdx.x * 64;
    const int Mrem = min(64, (NTOT - NN) - r0);
    const int tx = t & 15;            // 16 col-groups x 8
    const int ty = t >> 4;            // 16 row-groups x 4

    for (int f = t; f < 64 * 32; f += 256) {
        int row = f >> 5, c4 = (f & 31) * 4;
        if (row < Mrem)
            *(float4*)&rowb[row][c4] = *(const float4*)(xup + (size_t)(r0 + row) * CH + c4);
    }

    for (int l = 0; l < 3; l++) {
        float acc[4][8];
        #pragma unroll
        for (int i = 0; i < 4; i++)
            #pragma unroll
            for (int j = 0; j < 8; j++) acc[i][j] = 0.f;

        for (int k0 = 0; k0 < 128; k0 += 16) {
            __syncthreads();       // rowb writes settled / Bs free
            for (int f = t; f < 512; f += 256) {
                int kk = f >> 5, n4 = (f & 31) * 4;
                *(float4*)&Bs[kk][n4] = *(const float4*)(Wskip + (size_t)(k0 + kk) * 128 + n4);
            }
            __syncthreads();
            #pragma unroll
            for (int kk = 0; kk < 16; kk++) {
                const float4 b0 = *(const float4*)&Bs[kk][tx * 8];
                const float4 b1 = *(const float4*)&Bs[kk][tx * 8 + 4];
                const float bf[8] = {b0.x, b0.y, b0.z, b0.w, b1.x, b1.y, b1.z, b1.w};
                #pragma unroll
                for (int i = 0; i < 4; i++) {
                    const float af = rowb[ty * 4 + i][k0 + kk];
                    #pragma unroll
                    for (int j = 0; j < 8; j++)
                        acc[i][j] = fmaf(af, bf[j], acc[i][j]);
                }
            }
        }
        __syncthreads();           // all rowb reads done before overwrite
        const float* bS = bnS + l * 128;
        const float* bB = bnB + l * 128;
        #pragma unroll
        for (int i = 0; i < 4; i++) {
            const int row = ty * 4 + i;
            #pragma unroll
            for (int j = 0; j < 8; j++) {
                const int n = tx * 8 + j;
                float xv = acc[i][j] + bskip[n];
                xv = fmaf(xv, bS[n], bB[n]);
                rowb[row][n] = fmaxf(xv, 0.f);
            }
        }
        // next layer's leading __syncthreads() publishes rowb
    }
    __syncthreads();
    for (int f = t; f < 64 * 32; f += 256) {
        int row = f >> 5, c4 = (f & 31) * 4;
        if (row < Mrem)
            *(float4*)(h3up + (size_t)(r0 + row) * CH + c4) = *(const float4*)&rowb[row][c4];
    }
}

// ---------------------------------------------------------------------------
// fp32 tiled GEMM, 256 threads, BK=16.
// MODE 0 (ug): C = A*B + bias, dual dest: cols <512 -> C0 (u), >=512 -> C1
//              (raw lower skip; no BN).
// MODE 4 (comb'): C0 = relu(bn(A*B + Cold + (deg>0)*bias2))
// ---------------------------------------------------------------------------
template<int BM, int BN, int TM, int TN, int MODE>
__global__ __launch_bounds__(256) void gemm_fp32(
    const float* __restrict__ A, int lda,
    const float* __restrict__ B, int ldb,
    const float* __restrict__ bias, const float* __restrict__ bias2,
    const int* __restrict__ deg,
    const float* __restrict__ Cold,
    const float* __restrict__ bnS, const float* __restrict__ bnB,
    float* __restrict__ C0, int ldc0,
    float* __restrict__ C1, int ldc1,
    int M, int K)
{
    constexpr int BK = 16;
    __shared__ float As[BK][BM + 4];
    __shared__ float Bs[BK][BN + 4];
    const int t  = threadIdx.x;
    const int tx = t % (BN / TN);
    const int ty = t / (BN / TN);
    const int m0 = blockIdx.x * BM;
    const int n0 = blockIdx.y * BN;
    float acc[TM][TN];
    #pragma unroll
    for (int i = 0; i < TM; i++)
        #pragma unroll
        for (int j = 0; j < TN; j++) acc[i][j] = 0.f;

    for (int k0 = 0; k0 < K; k0 += BK) {
        #pragma unroll
        for (int f = t; f < BM * 4; f += 256) {
            int row = f >> 2, fc = f & 3;
            int gm = m0 + row;
            float4 v = make_float4(0.f, 0.f, 0.f, 0.f);
            if (gm < M) v = *(const float4*)(A + (size_t)gm * lda + k0 + fc * 4);
            As[fc * 4 + 0][row] = v.x;
            As[fc * 4 + 1][row] = v.y;
            As[fc * 4 + 2][row] = v.z;
            As[fc * 4 + 3][row] = v.w;
        }
        #pragma unroll
        for (int f = t; f < BK * (BN / 4); f += 256) {
            int kk = f / (BN / 4);
            int nn = (f % (BN / 4)) * 4;
            *(float4*)(&Bs[kk][nn]) = *(const float4*)(B + (size_t)(k0 + kk) * ldb + n0 + nn);
        }
        __syncthreads();
        #pragma unroll
        for (int kk = 0; kk < BK; kk++) {
            float af[TM], bf[TN];
            if constexpr (TM == 2) {
                float2 v = *(const float2*)&As[kk][ty * 2];
                af[0] = v.x; af[1] = v.y;
            } else {
                #pragma unroll
                for (int ii = 0; ii < TM; ii += 4) {
                    float4 v = *(const float4*)&As[kk][ty * TM + ii];
                    af[ii + 0] = v.x; af[ii + 1] = v.y; af[ii + 2] = v.z; af[ii + 3] = v.w;
                }
            }
            #pragma unroll
            for (int jj = 0; jj < TN; jj += 4) {
                float4 v = *(const float4*)&Bs[kk][tx * TN + jj];
                bf[jj + 0] = v.x; bf[jj + 1] = v.y; bf[jj + 2] = v.z; bf[jj + 3] = v.w;
            }
            #pragma unroll
            for (int i = 0; i < TM; i++)
                #pragma unroll
                for (int j = 0; j < TN; j++)
                    acc[i][j] = fmaf(af[i], bf[j], acc[i][j]);
        }
        __syncthreads();
    }
    // epilogue
    #pragma unroll
    for (int i = 0; i < TM; i++) {
        int gm = m0 + ty * TM + i;
        if (gm >= M) continue;
        const bool addB2 = (MODE == 4) ? (deg[gm] > 0) : false;
        #pragma unroll
        for (int j = 0; j < TN; j += 4) {
            const int nb = n0 + tx * TN + j;
            float4 v;
            float* vp = &v.x;
            if (MODE == 4) {
                const float4 old = *(const float4*)(Cold + (size_t)gm * ldc1 + nb);
                const float* op = &old.x;
                #pragma unroll
                for (int q = 0; q < 4; q++) {
                    const int n = nb + q;
                    float x = acc[i][j + q] + op[q];
                    if (addB2) x += bias2[n];
                    x = fmaf(x, bnS[n], bnB[n]);
                    vp[q] = fmaxf(x, 0.f);
                }
                *(float4*)(C0 + (size_t)gm * ldc0 + nb) = v;
            } else {
                #pragma unroll
                for (int q = 0; q < 4; q++)
                    vp[q] = acc[i][j + q] + bias[nb + q];
                if (nb < 512)
                    *(float4*)(C0 + (size_t)gm * ldc0 + nb) = v;
                else
                    *(float4*)(C1 + (size_t)gm * ldc1 + nb - 512) = v;
            }
        }
    }
}

// ---------------------------------------------------------------------------
// Attention: one block per dst node, chunked online softmax over CSR edges.
// ---------------------------------------------------------------------------
__global__ __launch_bounds__(256) void attn_kernel(
    const float* __restrict__ h,
    const float* __restrict__ u,
    float* __restrict__ g,
    const int* __restrict__ rowstart,
    const int* __restrict__ csr_src)
{
    __shared__ float h_lds[128 * 65];
    __shared__ __align__(16) float palpha[4 * 64 * 4];   // [ht][j][w]
    __shared__ __align__(16) float wT[64 * 4];           // [j][ht]
    __shared__ __align__(16) float scale_lds[4];
    __shared__ __align__(16) float s_lds[4];
    __shared__ __align__(16) float merge[128 * 4];
    __shared__ int src_lds[64];

    const int n  = blockIdx.x;
    const int t  = threadIdx.x;
    const int w  = t >> 6;      // wave id
    const int l  = t & 63;      // lane
    const int c  = t & 127;     // acc channel
    const int jh = t >> 7;      // acc j-half
    const int rs   = rowstart[n];
    const int degn = rowstart[n + 1] - rs;

    if (degn == 0) {
        g[(size_t)n * 512 + t] = 0.f;
        g[(size_t)n * 512 + 256 + t] = 0.f;
        return;
    }
    float u_reg0 = u[(size_t)n * 512 + ((l >> 5)) * 128 + 32 * w + (l & 31)];
    float u_reg1 = u[(size_t)n * 512 + ((l >> 5) + 2) * 128 + 32 * w + (l & 31)];

    float m_run = -INFINITY, s_run = 0.f;
    float4 acc4 = make_float4(0.f, 0.f, 0.f, 0.f);

    for (int base = 0; base < degn; base += 64) {
        const int len = min(64, degn - base);
        __syncthreads();
        if (t < len) src_lds[t] = csr_src[rs + base + t];
        __syncthreads();
        for (int f = t; f < len * 32; f += 256) {
            const int j = f >> 5, c4 = (f & 31) * 4;
            const float4 v = *(const float4*)(h + (size_t)src_lds[j] * CH + c4);
            h_lds[(c4 + 0) * 65 + j] = v.x;
            h_lds[(c4 + 1) * 65 + j] = v.y;
            h_lds[(c4 + 2) * 65 + j] = v.z;
            h_lds[(c4 + 3) * 65 + j] = v.w;
        }
        __syncthreads();
        {
            float p0 = 0.f, p1 = 0.f, p2 = 0.f, p3 = 0.f;
            #pragma unroll
            for (int dc = 0; dc < 32; dc++) {
                const float hv = h_lds[(32 * w + dc) * 65 + l];
                p0 = fmaf(rl_f(u_reg0, dc),      hv, p0);
                p1 = fmaf(rl_f(u_reg0, 32 + dc), hv, p1);
                p2 = fmaf(rl_f(u_reg1, dc),      hv, p2);
                p3 = fmaf(rl_f(u_reg1, 32 + dc), hv, p3);
            }
            palpha[(0 * 64 + l) * 4 + w] = p0;
            palpha[(1 * 64 + l) * 4 + w] = p1;
            palpha[(2 * 64 + l) * 4 + w] = p2;
            palpha[(3 * 64 + l) * 4 + w] = p3;
        }
        __syncthreads();
        {
            const float4 pa = *(const float4*)&palpha[(w * 64 + l) * 4];
            float alpha = (l < len) ? (pa.x + pa.y + pa.z + pa.w) : -INFINITY;
            float mx = alpha;
            #pragma unroll
            for (int d = 1; d < 64; d <<= 1) mx = fmaxf(mx, __shfl_xor(mx, d, 64));
            const float newm = fmaxf(m_run, mx);
            float e = (l < len) ? __expf(alpha - newm) : 0.f;
            float ss = e;
            #pragma unroll
            for (int d = 1; d < 64; d <<= 1) ss += __shfl_xor(ss, d, 64);
            const float sc = (m_run == -INFINITY) ? 0.f : __expf(m_run - newm);
            s_run = s_run * sc + ss;
            m_run = newm;
            wT[l * 4 + w] = e;
            if (l == 0) scale_lds[w] = sc;
        }
        __syncthreads();
        {
            const float4 scv = *(const float4*)scale_lds;
            acc4.x *= scv.x; acc4.y *= scv.y; acc4.z *= scv.z; acc4.w *= scv.w;
            const int j0 = jh * 32;
            const int j1 = min(len, j0 + 32);
            for (int j = j0; j < j1; j++) {
                const float hv = h_lds[c * 65 + j];
                const float4 wv = *(const float4*)&wT[j * 4];
                acc4.x = fmaf(wv.x, hv, acc4.x);
                acc4.y = fmaf(wv.y, hv, acc4.y);
                acc4.z = fmaf(wv.z, hv, acc4.z);
                acc4.w = fmaf(wv.w, hv, acc4.w);
            }
        }
    }
    if (l == 0) s_lds[w] = s_run;
    __syncthreads();
    if (jh == 1) *(float4*)&merge[c * 4] = acc4;
    __syncthreads();
    if (jh == 0) {
        const float4 o  = *(const float4*)&merge[c * 4];
        const float4 sv = *(const float4*)s_lds;
        g[(size_t)n * 512 + 0 * 128 + c] = (acc4.x + o.x) / (sv.x + 1e-16f);
        g[(size_t)n * 512 + 1 * 128 + c] = (acc4.y + o.y) / (sv.y + 1e-16f);
        g[(size_t)n * 512 + 2 * 128 + c] = (acc4.z + o.z) / (sv.z + 1e-16f);
        g[(size_t)n * 512 + 3 * 128 + c] = (acc4.w + o.w) / (sv.w + 1e-16f);
    }
}

// ---------------------------------------------------------------------------
// Radix-select sort-pool (exact, stable-tie; keys post-ReLU => uint-monotone)
// ---------------------------------------------------------------------------
__global__ __launch_bounds__(256) void radix_pool_kernel(
    const float* __restrict__ h3, const float* __restrict__ age,
    float* __restrict__ z)
{
    __shared__ unsigned int keys[NN];
    __shared__ int hist[256];
    __shared__ int sbuf[256];
    __shared__ unsigned int sel_prefix;
    __shared__ int sel_need;
    __shared__ int gt_counter;
    __shared__ unsigned int cand_key[30];
    __shared__ int cand_idx[30];
    __shared__ int order[30];

    const int b = blockIdx.x;
    const int t = threadIdx.x;

    for (int i = t; i < NN; i += 256)
        keys[i] = __float_as_uint(h3[((size_t)b * NN + i) * CH + 127]);
    if (t == 0) { sel_prefix = 0u; sel_need = 30; gt_counter = 0; }
    __syncthreads();

    for (int r = 3; r >= 0; r--) {
        hist[t] = 0;
        __syncthreads();
        const int shift = r * 8;
        const unsigned int pmask = (r == 3) ? 0u : (0xFFFFFFFFu << ((r + 1) * 8));
        const unsigned int pref = sel_prefix;
        const int need = sel_need;
        for (int i = t; i < NN; i += 256) {
            unsigned int k = keys[i];
            if ((k & pmask) == pref)
                atomicAdd(&hist[(k >> shift) & 255u], 1);
        }
        __syncthreads();
        sbuf[t] = hist[255 - t];
        __syncthreads();
        for (int d = 1; d < 256; d <<= 1) {
            int o = (t >= d) ? sbuf[t - d] : 0;
            __syncthreads();
            sbuf[t] += o;
            __syncthreads();
        }
        {
            const int v = t;
            const int ge = sbuf[255 - v];
            const int gt = ge - hist[v];
            if (gt < need && need <= ge) {
                sel_prefix = pref | ((unsigned int)v << shift);
                sel_need = need - gt;
            }
        }
        __syncthreads();
    }

    const unsigned int T = sel_prefix;
    const int need_eq = sel_need;
    const int n_gt = 30 - need_eq;

    for (int i = t; i < NN; i += 256) {
        unsigned int k = keys[i];
        if (k > T) {
            int p = atomicAdd(&gt_counter, 1);
            cand_key[p] = k; cand_idx[p] = i;
        }
    }
    {
        const int CHK = (NN + 255) / 256;
        const int i0 = t * CHK, i1 = min(NN, i0 + CHK);
        int local = 0;
        for (int i = i0; i < i1; i++) if (keys[i] == T) local++;
        sbuf[t] = local;
        __syncthreads();
        for (int d = 1; d < 256; d <<= 1) {
            int o = (t >= d) ? sbuf[t - d] : 0;
            __syncthreads();
            sbuf[t] += o;
            __syncthreads();
        }
        int rank = (t == 0) ? 0 : sbuf[t - 1];
        for (int i = i0; i < i1; i++) {
            if (keys[i] == T) {
                if (rank < need_eq) { cand_key[n_gt + rank] = T; cand_idx[n_gt + rank] = i; }
                rank++;
            }
        }
    }
    __syncthreads();
    if (t < 30) {
        const unsigned int mk = cand_key[t];
        const int mi = cand_idx[t];
        int rk = 0;
        for (int j = 0; j < 30; j++) {
            const unsigned int ok = cand_key[j];
            const int oi = cand_idx[j];
            if (ok > mk || (ok == mk && oi < mi)) rk++;
        }
        order[rk] = t;
    }
    __syncthreads();
    for (int f = t; f < 30 * CH; f += 256) {
        int kk = f >> 7, cc = f & 127;
        z[(size_t)b * 3841 + f] = h3[((size_t)b * NN + cand_idx[order[kk]]) * CH + cc];
    }
    if (t == 0) z[(size_t)b * 3841 + 3840] = age[b];
}

// ---------------------------------------------------------------------------
// MLP head
// ---------------------------------------------------------------------------
__global__ __launch_bounds__(256) void mlp1_kernel(
    const float* __restrict__ z, const float* __restrict__ W1,
    float* __restrict__ zh)
{
    __shared__ float zs[256];
    const int b  = blockIdx.x >> 4;
    const int ic = blockIdx.x & 15;
    const int t  = threadIdx.x;
    const int i0 = ic * 241;
    const int i1 = min(3841, i0 + 241);
    float a0 = 0.f, a1 = 0.f;
    for (int cb = i0; cb < i1; cb += 256) {
        int cl = min(256, i1 - cb);
        __syncthreads();
        if (t < cl) zs[t] = z[(size_t)b * 3841 + cb + t];
        __syncthreads();
        #pragma unroll 4
        for (int q = 0; q < cl; q++) {
            float zv = zs[q];
            const float* wp = W1 + (size_t)(cb + q) * 512;
            a0 = fmaf(zv, wp[t], a0);
            a1 = fmaf(zv, wp[t + 256], a1);
        }
    }
    atomicAdd(&zh[(size_t)b * 512 + t], a0);
    atomicAdd(&zh[(size_t)b * 512 + t + 256], a1);
}

__global__ __launch_bounds__(256) void mlp2_kernel(
    const float* __restrict__ zh, const float* __restrict__ b1,
    const float* __restrict__ W2, const float* __restrict__ b2,
    float* __restrict__ out)
{
    __shared__ float r0[256], r1[256];
    const int b = blockIdx.x;
    const int t = threadIdx.x;
    float a0 = 0.f, a1 = 0.f;
    for (int j = t; j < 512; j += 256) {
        float v = fmaxf(zh[(size_t)b * 512 + j] + b1[j], 0.f);
        a0 = fmaf(v, W2[j * 2 + 0], a0);
        a1 = fmaf(v, W2[j * 2 + 1], a1);
    }
    r0[t] = a0; r1[t] = a1; __syncthreads();
    for (int s = 128; s > 0; s >>= 1) {
        if (t < s) { r0[t] += r0[t + s]; r1[t] += r1[t + s]; }
        __syncthreads();
    }
    if (t == 0) {
        float l0 = r0[0] + b2[0], l1 = r1[0] + b2[1];
        float m = fmaxf(l0, l1);
        float lse = m + logf(__expf(l0 - m) + __expf(l1 - m));
        out[b * 2 + 0] = l0 - lse;
        out[b * 2 + 1] = l1 - lse;
    }
}

// ---------------------------------------------------------------------------
extern "C" void kernel_launch(void* const* d_in, const int* in_sizes, int n_in,
                              void* d_out, int out_size, void* d_ws, size_t ws_size,
                              hipStream_t stream) {
    const float* x     = (const float*)d_in[0];
    const int*   ei    = (const int*)d_in[1];
    const float* age   = (const float*)d_in[2];
    const float* Wq    = (const float*)d_in[3];
    const float* bq    = (const float*)d_in[4];
    const float* Wk    = (const float*)d_in[5];
    // d_in[6] = bk: provably softmax-invariant, unused.
    const float* Wv    = (const float*)d_in[7];
    const float* bv    = (const float*)d_in[8];
    const float* Wskip = (const float*)d_in[9];
    const float* bskip = (const float*)d_in[10];
    const float* bn_g  = (const float*)d_in[11];
    const float* bn_b  = (const float*)d_in[12];
    const float* bn_m  = (const float*)d_in[13];
    const float* bn_v  = (const float*)d_in[14];
    const float* W1    = (const float*)d_in[15];
    const float* b1    = (const float*)d_in[16];
    const float* W2    = (const float*)d_in[17];
    const float* b2    = (const float*)d_in[18];

    float* ws = (float*)d_ws;
    float* h3      = ws;                     // 10,240,000 (80000x128)
    float* hlowA   = h3 + 10240000;          // 1,280,000
    float* hlowB   = hlowA + 1280000;        // 1,280,000
    float* u       = hlowB + 1280000;        // 5,120,000 (g aliases u)
    float* skipraw = u + 5120000;            // 1,280,000
    float* Bcat    = skipraw + 1280000;      // 81,920
    float* biascat = Bcat + 81920;           // 640
    float* Wcomb   = biascat + 640;          // 65,536
    float* bvbar   = Wcomb + 65536;          // 128
    float* bnS     = bvbar + 128;            // 384
    float* bnB     = bnS + 384;              // 384
    float* zbuf    = bnB + 384;              // 30,728
    float* zh      = zbuf + 30728;           // 4,096
    int* deg      = (int*)(zh + 4096);       // 10,000
    int* cursor   = deg + NN;                // 10,000
    int* rowstart = cursor + NN;             // 10,001
    int* csr_src  = rowstart + NN + 1;       // 320,000

    const int* srcI = ei;
    const int* dstI = ei + EE;

    hipMemsetAsync(deg, 0, sizeof(int) * (2 * NN), stream);   // deg + cursor
    hipMemsetAsync(zh, 0, sizeof(float) * 4096, stream);

    precompute_kernel<<<581, 256, 0, stream>>>(Wq, bq, Wk, Wv, bv, Wskip, bskip,
                                               bn_g, bn_b, bn_m, bn_v,
                                               Bcat, biascat, Wcomb, bvbar, bnS, bnB);
    count_kernel<<<1250, 256, 0, stream>>>(dstI, deg);
    scan_kernel<<<1, 1024, 0, stream>>>(deg, rowstart);
    scatter_kernel<<<1250, 256, 0, stream>>>(srcI, dstI, rowstart, cursor, csr_src);

    // upper 70000 rows: all 3 layers fused, writes h3[NN:]
    skip3_kernel<<<1094, 256, 0, stream>>>(x + (size_t)NN * CH, Wskip, bskip,
                                           bnS, bnB, h3 + (size_t)NN * CH);

    const float* hcur = x;                   // lower-row slice (rows 0..NN-1)
    for (int l = 0; l < 3; l++) {
        float* dest = (l == 0) ? hlowA : (l == 1) ? hlowB : h3;  // h3 rows 0..NN-1
        // [u | raw skip] = h_low @ [Pm | Wskip] + [r | bskip]   (1570 blocks)
        gemm_fp32<64, 64, 4, 4, 0><<<dim3(157, 10), 256, 0, stream>>>(
            hcur, CH, Bcat, 640, biascat, nullptr, nullptr, nullptr,
            nullptr, nullptr, u, 512, skipraw, CH, NN, 128);
        // g = softmax-weighted neighbor sums of h, aliased onto u
        attn_kernel<<<NN, 256, 0, stream>>>(hcur, u, u, rowstart, csr_src);
        // h_next = relu(bn(g @ Wvstack + skipraw + (deg>0)*bvbar))  (626 blocks)
        gemm_fp32<32, 64, 2, 4, 4><<<dim3(313, 2), 256, 0, stream>>>(
            u, 512, Wcomb, CH, nullptr, bvbar, deg, skipraw,
            bnS + l * 128, bnB + l * 128, dest, CH, nullptr, CH, NN, 512);
        hcur = dest;
    }
    radix_pool_kernel<<<8, 256, 0, stream>>>(h3, age, zbuf);
    mlp1_kernel<<<128, 256, 0, stream>>>(zbuf, W1, zh);
    mlp2_kernel<<<8, 256, 0, stream>>>(zh, b1, W2, b2, (float*)d_out);
}